// Round 1
// baseline (521.166 us; speedup 1.0000x reference)
//
#include <hip/hip_runtime.h>

#define Bn 128
#define Nn 128
#define Fn 41
#define INNERn 40
#define OUTn 512
#define SLAB (Nn*Fn)   // 5248 floats = 20992 B, 16B-aligned per block

// Kernel 1: one block per (b,i) row-slab. Produces:
//   X0[b,i,c]   = g[b,i,i,c]                (diag attrs core)
//   pre1[b,i,c] = sum_j g[b,i,j,c], c<40
//   S[b,j]     += g[b,i,j,40] + (i==j)      (column sums of bonds + eye)
__global__ __launch_bounds__(256) void k1_reduce(
    const float* __restrict__ g, float* __restrict__ X0,
    float* __restrict__ pre1, float* __restrict__ S)
{
    __shared__ float lds[SLAB];
    __shared__ float part[6*INNERn];
    const int t = threadIdx.x;
    const int blk = blockIdx.x;
    const int b = blk >> 7;
    const int i = blk & 127;

    const float4* __restrict__ src = (const float4*)(g + (size_t)blk * SLAB);
    float4* dst = (float4*)lds;
    #pragma unroll
    for (int it = 0; it < 5; ++it) dst[t + 256*it] = src[t + 256*it];
    if (t < (SLAB/4 - 1280)) dst[1280 + t] = src[1280 + t];   // 1312 total
    __syncthreads();

    // channel partial sums: 6 groups x 40 channels
    if (t < 240) {
        const int grp = t / 40;
        const int f = t - grp*40;
        float s = 0.f;
        for (int j = grp; j < Nn; j += 6) s += lds[j*Fn + f];
        part[grp*INNERn + f] = s;
    }
    // bonds column contributions (this block holds bonds[i, j] for all j)
    if (t < 128) {
        float v = lds[t*Fn + 40] + ((t == i) ? 1.f : 0.f);
        atomicAdd(&S[b*Nn + t], v);
    }
    // diagonal attrs core
    if (t < 40) {
        X0[(size_t)blk*INNERn + t] = lds[i*Fn + t];
    }
    __syncthreads();
    if (t < 40) {
        float s = part[t] + part[INNERn + t] + part[2*INNERn + t]
                + part[3*INNERn + t] + part[4*INNERn + t] + part[5*INNERn + t];
        pre1[(size_t)blk*INNERn + t] = s;
    }
}

// Kernel 2: per 32 rows, compute
//   core1 = pre1 @ W1 + b1
//   pre2  = pre1 + S * (core1 - attrs0)
//   core2 = pre2 @ W2 + b2
__global__ __launch_bounds__(256) void k2_chain(
    const float* __restrict__ pre1, const float* __restrict__ X0,
    const float* __restrict__ S, const float* __restrict__ Wi,
    const float* __restrict__ bi, float* __restrict__ X1, float* __restrict__ X2)
{
    __shared__ float W1[INNERn*INNERn], W2[INNERn*INNERn];
    __shared__ float A[32*INNERn];
    __shared__ float T[32*INNERn];
    __shared__ float Sv[32];
    const int t = threadIdx.x;
    const size_t row0 = (size_t)blockIdx.x * 32;

    for (int idx = t; idx < INNERn*INNERn; idx += 256) {
        W1[idx] = Wi[INNERn*INNERn + idx];      // W_inner[1]
        W2[idx] = Wi[2*INNERn*INNERn + idx];    // W_inner[2]
    }
    for (int idx = t; idx < 32*INNERn; idx += 256) {
        A[idx] = pre1[row0*INNERn + idx];
        T[idx] = X0[row0*INNERn + idx];
    }
    if (t < 32) Sv[t] = S[row0 + t];
    __syncthreads();

    float c1[5];
    #pragma unroll
    for (int p = 0; p < 5; ++p) {
        int idx = t + 256*p;
        int r = idx / INNERn, c = idx - r*INNERn;
        float acc = bi[INNERn + c];             // b_inner[1][0][c]
        for (int k = 0; k < INNERn; ++k) acc = fmaf(A[r*INNERn + k], W1[k*INNERn + c], acc);
        c1[p] = acc;
    }
    __syncthreads();
    #pragma unroll
    for (int p = 0; p < 5; ++p) {
        int idx = t + 256*p;
        int r = idx / INNERn;
        X1[row0*INNERn + idx] = c1[p];
        A[idx] = A[idx] + Sv[r] * (c1[p] - T[idx]);   // pre2
    }
    __syncthreads();
    #pragma unroll
    for (int p = 0; p < 5; ++p) {
        int idx = t + 256*p;
        int r = idx / INNERn, c = idx - r*INNERn;
        float acc = bi[2*INNERn + c];           // b_inner[2][0][c]
        for (int k = 0; k < INNERn; ++k) acc = fmaf(A[r*INNERn + k], W2[k*INNERn + c], acc);
        X2[row0*INNERn + idx] = acc;
    }
}

// Kernel 3: for each (d, b, 32-row chunk): logits = X @ W_output[d] + b_output[d],
// row softmax, sum over rows, atomically accumulate into out[b, :].
// Block: 4 waves x 8 rows each; lane holds 8 cols (lane + 64u), 8x8 fp32 accum.
__global__ __launch_bounds__(256) void k3_softmax(
    const float* __restrict__ X, const float* __restrict__ Wo,
    const float* __restrict__ bo_g, float* __restrict__ out)
{
    __shared__ float lx[32*INNERn];
    __shared__ float lacc[OUTn];
    const int t = threadIdx.x;
    const int lane = t & 63;
    const int w = t >> 6;
    const int bx = blockIdx.x;
    const int d = bx >> 9;
    const int rem = bx & 511;
    const int b = rem >> 2;
    const int chunk = rem & 3;

    const float* __restrict__ Xb = X + (((size_t)d*Bn + b)*Nn + chunk*32)*INNERn;
    for (int idx = t; idx < 32*INNERn; idx += 256) lx[idx] = Xb[idx];
    for (int idx = t; idx < OUTn; idx += 256) lacc[idx] = 0.f;
    __syncthreads();

    const float* __restrict__ W = Wo + (size_t)d*INNERn*OUTn;
    float acc[8][8];
    #pragma unroll
    for (int r = 0; r < 8; ++r)
        #pragma unroll
        for (int u = 0; u < 8; ++u) acc[r][u] = 0.f;

    for (int k = 0; k < INNERn; ++k) {
        float wv[8];
        #pragma unroll
        for (int u = 0; u < 8; ++u) wv[u] = W[k*OUTn + lane + 64*u];   // coalesced, L1/L2-hot
        #pragma unroll
        for (int r = 0; r < 8; ++r) {
            float a = lx[(w*8 + r)*INNERn + k];                        // LDS broadcast
            #pragma unroll
            for (int u = 0; u < 8; ++u) acc[r][u] = fmaf(a, wv[u], acc[r][u]);
        }
    }

    float bv[8];
    #pragma unroll
    for (int u = 0; u < 8; ++u) bv[u] = bo_g[d*OUTn + lane + 64*u];
    float colacc[8];
    #pragma unroll
    for (int u = 0; u < 8; ++u) colacc[u] = 0.f;

    #pragma unroll
    for (int r = 0; r < 8; ++r) {
        float lg[8];
        float m = -3.4e38f;
        #pragma unroll
        for (int u = 0; u < 8; ++u) { lg[u] = acc[r][u] + bv[u]; m = fmaxf(m, lg[u]); }
        #pragma unroll
        for (int off = 32; off > 0; off >>= 1) m = fmaxf(m, __shfl_xor(m, off));
        float s = 0.f, e[8];
        #pragma unroll
        for (int u = 0; u < 8; ++u) { e[u] = __expf(lg[u] - m); s += e[u]; }
        #pragma unroll
        for (int off = 32; off > 0; off >>= 1) s += __shfl_xor(s, off);
        float inv = 1.f / s;
        #pragma unroll
        for (int u = 0; u < 8; ++u) colacc[u] = fmaf(e[u], inv, colacc[u]);
    }

    #pragma unroll
    for (int u = 0; u < 8; ++u) atomicAdd(&lacc[lane + 64*u], colacc[u]);
    __syncthreads();
    for (int idx = t; idx < OUTn; idx += 256) atomicAdd(&out[(size_t)b*OUTn + idx], lacc[idx]);
}

extern "C" void kernel_launch(void* const* d_in, const int* in_sizes, int n_in,
                              void* d_out, int out_size, void* d_ws, size_t ws_size,
                              hipStream_t stream) {
    const float* g        = (const float*)d_in[0];  // (B,N,N,F)
    const float* W_inner  = (const float*)d_in[1];  // (3,40,40)
    const float* b_inner  = (const float*)d_in[2];  // (3,1,40)
    const float* W_output = (const float*)d_in[3];  // (3,40,512)
    const float* b_output = (const float*)d_in[4];  // (3,1,512)
    float* out = (float*)d_out;                     // (B,512) fp32
    float* ws  = (float*)d_ws;

    // ws layout (floats): X[3][B*N][40] | pre1[B*N][40] | S[B*N]
    const size_t nBN = (size_t)Bn * Nn;
    float* X    = ws;
    float* X0   = X;
    float* X1   = X + nBN * INNERn;
    float* X2   = X + 2 * nBN * INNERn;
    float* pre1 = X + 3 * nBN * INNERn;
    float* S    = pre1 + nBN * INNERn;

    hipMemsetAsync(S, 0, nBN * sizeof(float), stream);
    hipMemsetAsync(d_out, 0, (size_t)out_size * sizeof(float), stream);

    k1_reduce<<<Bn*Nn, 256, 0, stream>>>(g, X0, pre1, S);
    k2_chain<<<(Bn*Nn)/32, 256, 0, stream>>>(pre1, X0, S, W_inner, b_inner, X1, X2);
    k3_softmax<<<3*Bn*4, 256, 0, stream>>>(X, W_output, b_output, out);
}

// Round 2
// 507.917 us; speedup vs baseline: 1.0261x; 1.0261x over previous
//
#include <hip/hip_runtime.h>

#define Bn 128
#define Nn 128
#define Fn 41
#define INNERn 40
#define OUTn 512
#define SLAB (Nn*Fn)   // 5248 floats = 20992 B, 16B-aligned per block

// Kernel 1: one block per (b,i) row-slab. Produces:
//   X0[b,i,c]   = g[b,i,i,c]                (diag attrs core, read direct from global)
//   pre1[b,i,c] = sum_j g[b,i,j,c], c<40
//   S[b,j]     += g[b,i,j,40] + (i==j)      (column sums of bonds + eye)
__global__ __launch_bounds__(256) void k1_reduce(
    const float* __restrict__ g, float* __restrict__ X0,
    float* __restrict__ pre1, float* __restrict__ S)
{
    __shared__ float lds[SLAB];
    __shared__ float part[6*INNERn];
    const int t = threadIdx.x;
    const int blk = blockIdx.x;
    const int b = blk >> 7;
    const int i = blk & 127;

    // diag attrs core: direct global read, issued before the barrier (overlaps staging)
    if (t < 40) {
        X0[(size_t)blk*INNERn + t] = g[(size_t)blk*SLAB + i*Fn + t];
    }

    const float4* __restrict__ src = (const float4*)(g + (size_t)blk * SLAB);
    float4* dst = (float4*)lds;
    #pragma unroll
    for (int it = 0; it < 5; ++it) dst[t + 256*it] = src[t + 256*it];
    if (t < (SLAB/4 - 1280)) dst[1280 + t] = src[1280 + t];   // 1312 total
    __syncthreads();

    // channel partial sums: 6 groups x 40 channels
    if (t < 240) {
        const int grp = t / 40;
        const int f = t - grp*40;
        float s = 0.f;
        #pragma unroll 4
        for (int j = grp; j < Nn; j += 6) s += lds[j*Fn + f];
        part[grp*INNERn + f] = s;
    }
    // bonds column contributions (this block holds bonds[i, j] for all j)
    if (t < 128) {
        float v = lds[t*Fn + 40] + ((t == i) ? 1.f : 0.f);
        atomicAdd(&S[b*Nn + t], v);
    }
    __syncthreads();
    if (t < 40) {
        float s = part[t] + part[INNERn + t] + part[2*INNERn + t]
                + part[3*INNERn + t] + part[4*INNERn + t] + part[5*INNERn + t];
        pre1[(size_t)blk*INNERn + t] = s;
    }
}

// Kernel 2: per 16 rows (1024 blocks -> 4 blocks/CU), compute
//   core1 = pre1 @ W1 + b1
//   pre2  = pre1 + S * (core1 - attrs0)
//   core2 = pre2 @ W2 + b2
__global__ __launch_bounds__(256) void k2_chain(
    const float* __restrict__ pre1, const float* __restrict__ X0,
    const float* __restrict__ S, const float* __restrict__ Wi,
    const float* __restrict__ bi, float* __restrict__ X1, float* __restrict__ X2)
{
    __shared__ float W1[INNERn*INNERn], W2[INNERn*INNERn];
    __shared__ float A[16*INNERn];
    __shared__ float T[16*INNERn];
    __shared__ float Sv[16];
    const int t = threadIdx.x;
    const size_t row0 = (size_t)blockIdx.x * 16;

    for (int idx = t; idx < INNERn*INNERn; idx += 256) {
        W1[idx] = Wi[INNERn*INNERn + idx];      // W_inner[1]
        W2[idx] = Wi[2*INNERn*INNERn + idx];    // W_inner[2]
    }
    for (int idx = t; idx < 16*INNERn; idx += 256) {
        A[idx] = pre1[row0*INNERn + idx];
        T[idx] = X0[row0*INNERn + idx];
    }
    if (t < 16) Sv[t] = S[row0 + t];
    __syncthreads();

    float c1[3];
    #pragma unroll
    for (int p = 0; p < 3; ++p) {
        int idx = t + 256*p;
        if (idx < 16*INNERn) {
            int r = idx / INNERn, c = idx - r*INNERn;
            float acc = bi[INNERn + c];             // b_inner[1][0][c]
            #pragma unroll 4
            for (int k = 0; k < INNERn; ++k) acc = fmaf(A[r*INNERn + k], W1[k*INNERn + c], acc);
            c1[p] = acc;
        }
    }
    __syncthreads();
    #pragma unroll
    for (int p = 0; p < 3; ++p) {
        int idx = t + 256*p;
        if (idx < 16*INNERn) {
            int r = idx / INNERn;
            X1[row0*INNERn + idx] = c1[p];
            A[idx] = A[idx] + Sv[r] * (c1[p] - T[idx]);   // pre2
        }
    }
    __syncthreads();
    #pragma unroll
    for (int p = 0; p < 3; ++p) {
        int idx = t + 256*p;
        if (idx < 16*INNERn) {
            int r = idx / INNERn, c = idx - r*INNERn;
            float acc = bi[2*INNERn + c];           // b_inner[2][0][c]
            #pragma unroll 4
            for (int k = 0; k < INNERn; ++k) acc = fmaf(A[r*INNERn + k], W2[k*INNERn + c], acc);
            X2[row0*INNERn + idx] = acc;
        }
    }
}

// Kernel 3: for each (d, b, 32-row chunk): logits = X @ W_output[d] + b_output[d],
// row softmax, sum over rows, accumulate into out[b, :].
// Lane owns 8 CONTIGUOUS cols (lane*8..lane*8+7) -> W loads are 2x dwordx4 per k.
// Per-wave private LDS accumulator segments (no LDS atomics, no bank aliasing).
__global__ __launch_bounds__(256) void k3_softmax(
    const float* __restrict__ X, const float* __restrict__ Wo,
    const float* __restrict__ bo_g, float* __restrict__ out)
{
    __shared__ float lx[32*INNERn];
    __shared__ float lacc4[4*OUTn];
    const int t = threadIdx.x;
    const int lane = t & 63;
    const int w = t >> 6;
    const int bx = blockIdx.x;
    const int d = bx >> 9;
    const int rem = bx & 511;
    const int b = rem >> 2;
    const int chunk = rem & 3;

    const float* __restrict__ Xb = X + (((size_t)d*Bn + b)*Nn + chunk*32)*INNERn;
    for (int idx = t; idx < 32*INNERn; idx += 256) lx[idx] = Xb[idx];
    __syncthreads();

    const float* __restrict__ W = Wo + (size_t)d*INNERn*OUTn + lane*8;
    float acc[8][8];
    #pragma unroll
    for (int r = 0; r < 8; ++r)
        #pragma unroll
        for (int u = 0; u < 8; ++u) acc[r][u] = 0.f;

    for (int k = 0; k < INNERn; ++k) {
        const float4* __restrict__ wp = (const float4*)(W + k*OUTn);
        float4 w0 = wp[0];
        float4 w1 = wp[1];
        float wv[8] = {w0.x, w0.y, w0.z, w0.w, w1.x, w1.y, w1.z, w1.w};
        #pragma unroll
        for (int r = 0; r < 8; ++r) {
            float a = lx[(w*8 + r)*INNERn + k];                        // LDS broadcast
            #pragma unroll
            for (int u = 0; u < 8; ++u) acc[r][u] = fmaf(a, wv[u], acc[r][u]);
        }
    }

    const float4* __restrict__ bp = (const float4*)(bo_g + d*OUTn + lane*8);
    float4 b0 = bp[0];
    float4 b1 = bp[1];
    float bv[8] = {b0.x, b0.y, b0.z, b0.w, b1.x, b1.y, b1.z, b1.w};
    float colacc[8];
    #pragma unroll
    for (int u = 0; u < 8; ++u) colacc[u] = 0.f;

    #pragma unroll
    for (int r = 0; r < 8; ++r) {
        float lg[8];
        float m = -3.4e38f;
        #pragma unroll
        for (int u = 0; u < 8; ++u) { lg[u] = acc[r][u] + bv[u]; m = fmaxf(m, lg[u]); }
        #pragma unroll
        for (int off = 32; off > 0; off >>= 1) m = fmaxf(m, __shfl_xor(m, off));
        float s = 0.f, e[8];
        #pragma unroll
        for (int u = 0; u < 8; ++u) { e[u] = __expf(lg[u] - m); s += e[u]; }
        #pragma unroll
        for (int off = 32; off > 0; off >>= 1) s += __shfl_xor(s, off);
        float inv = 1.f / s;
        #pragma unroll
        for (int u = 0; u < 8; ++u) colacc[u] = fmaf(e[u], inv, colacc[u]);
    }

    // per-wave private segment: plain stores, fully contiguous per lane
    #pragma unroll
    for (int u = 0; u < 8; ++u) lacc4[w*OUTn + lane*8 + u] = colacc[u];
    __syncthreads();
    for (int idx = t; idx < OUTn; idx += 256) {
        float s = lacc4[idx] + lacc4[OUTn + idx] + lacc4[2*OUTn + idx] + lacc4[3*OUTn + idx];
        atomicAdd(&out[(size_t)b*OUTn + idx], s);
    }
}

extern "C" void kernel_launch(void* const* d_in, const int* in_sizes, int n_in,
                              void* d_out, int out_size, void* d_ws, size_t ws_size,
                              hipStream_t stream) {
    const float* g        = (const float*)d_in[0];  // (B,N,N,F)
    const float* W_inner  = (const float*)d_in[1];  // (3,40,40)
    const float* b_inner  = (const float*)d_in[2];  // (3,1,40)
    const float* W_output = (const float*)d_in[3];  // (3,40,512)
    const float* b_output = (const float*)d_in[4];  // (3,1,512)
    float* out = (float*)d_out;                     // (B,512) fp32
    float* ws  = (float*)d_ws;

    // ws layout (floats): X[3][B*N][40] | pre1[B*N][40] | S[B*N]
    const size_t nBN = (size_t)Bn * Nn;
    float* X    = ws;
    float* X0   = X;
    float* X1   = X + nBN * INNERn;
    float* X2   = X + 2 * nBN * INNERn;
    float* pre1 = X + 3 * nBN * INNERn;
    float* S    = pre1 + nBN * INNERn;

    hipMemsetAsync(S, 0, nBN * sizeof(float), stream);
    hipMemsetAsync(d_out, 0, (size_t)out_size * sizeof(float), stream);

    k1_reduce<<<Bn*Nn, 256, 0, stream>>>(g, X0, pre1, S);
    k2_chain<<<(Bn*Nn)/16, 256, 0, stream>>>(pre1, X0, S, W_inner, b_inner, X1, X2);
    k3_softmax<<<3*Bn*4, 256, 0, stream>>>(X, W_output, b_output, out);
}

// Round 3
// 504.293 us; speedup vs baseline: 1.0335x; 1.0072x over previous
//
#include <hip/hip_runtime.h>

#define Bn 128
#define Nn 128
#define Fn 41
#define INNERn 40
#define OUTn 512
#define SLAB (Nn*Fn)   // 5248 floats = 1312 float4 slots per (b,i) row-slab

// Kernel 0: zero S (16384 floats) and out (65536 floats) in one launch.
__global__ __launch_bounds__(256) void k0_zero(float* __restrict__ S, float* __restrict__ out) {
    const int idx = blockIdx.x * 256 + threadIdx.x;   // grid = 256 blocks -> 65536 threads
    if (idx < Bn*Nn) S[idx] = 0.f;
    out[idx] = 0.f;                                    // exactly Bn*OUTn = 65536
}

// Kernel 1: one block per (b,i) row-slab. Async-stage the 21 KB slab into LDS
// via global_load_lds (width 16, no VGPR round-trip), then:
//   X0[b,i,c]   = g[b,i,i,c]
//   pre1[b,i,c] = sum_j g[b,i,j,c], c<40
//   S[b,j]     += g[b,i,j,40] + (i==j)
__global__ __launch_bounds__(256) void k1_reduce(
    const float* __restrict__ g, float* __restrict__ X0,
    float* __restrict__ pre1, float* __restrict__ S)
{
    __shared__ float lds[SLAB];
    __shared__ float part[6*INNERn];
    const int t = threadIdx.x;
    const int lane = t & 63;
    const int w = t >> 6;
    const int blk = blockIdx.x;
    const int b = blk >> 7;
    const int i = blk & 127;

    const float* __restrict__ src = g + (size_t)blk * SLAB;

    // 1312 float4 slots: 5 full rounds of 256 + 32-slot tail (wave 0, lanes 0..31).
    // LDS dest is wave-uniform base + lane*16 — layout matches slot order exactly.
    #pragma unroll
    for (int it = 0; it < 5; ++it) {
        const int slotbase = it*256 + w*64;
        __builtin_amdgcn_global_load_lds(
            (const __attribute__((address_space(1))) unsigned int*)(src + (size_t)(slotbase + lane)*4),
            (__attribute__((address_space(3))) unsigned int*)(lds + (size_t)slotbase*4),
            16, 0, 0);
    }
    if (w == 0 && lane < 32) {
        __builtin_amdgcn_global_load_lds(
            (const __attribute__((address_space(1))) unsigned int*)(src + (size_t)(1280 + lane)*4),
            (__attribute__((address_space(3))) unsigned int*)(lds + (size_t)1280*4),
            16, 0, 0);
    }
    __syncthreads();

    // channel partial sums: 6 groups x 40 channels
    if (t < 240) {
        const int grp = t / 40;
        const int f = t - grp*40;
        float s = 0.f;
        #pragma unroll 4
        for (int j = grp; j < Nn; j += 6) s += lds[j*Fn + f];
        part[grp*INNERn + f] = s;
    }
    // bonds column contributions (this block holds bonds[i, j] for all j)
    if (t < 128) {
        float v = lds[t*Fn + 40] + ((t == i) ? 1.f : 0.f);
        atomicAdd(&S[b*Nn + t], v);
    }
    // diagonal attrs core
    if (t < 40) {
        X0[(size_t)blk*INNERn + t] = lds[i*Fn + t];
    }
    __syncthreads();
    if (t < 40) {
        float s = part[t] + part[INNERn + t] + part[2*INNERn + t]
                + part[3*INNERn + t] + part[4*INNERn + t] + part[5*INNERn + t];
        pre1[(size_t)blk*INNERn + t] = s;
    }
}

// Kernel 2: per 16 rows (1024 blocks), compute
//   core1 = pre1 @ W1 + b1
//   pre2  = pre1 + S * (core1 - attrs0)
//   core2 = pre2 @ W2 + b2
__global__ __launch_bounds__(256) void k2_chain(
    const float* __restrict__ pre1, const float* __restrict__ X0,
    const float* __restrict__ S, const float* __restrict__ Wi,
    const float* __restrict__ bi, float* __restrict__ X1, float* __restrict__ X2)
{
    __shared__ float W1[INNERn*INNERn], W2[INNERn*INNERn];
    __shared__ float A[16*INNERn];
    __shared__ float T[16*INNERn];
    __shared__ float Sv[16];
    const int t = threadIdx.x;
    const size_t row0 = (size_t)blockIdx.x * 16;

    for (int idx = t; idx < INNERn*INNERn; idx += 256) {
        W1[idx] = Wi[INNERn*INNERn + idx];      // W_inner[1]
        W2[idx] = Wi[2*INNERn*INNERn + idx];    // W_inner[2]
    }
    for (int idx = t; idx < 16*INNERn; idx += 256) {
        A[idx] = pre1[row0*INNERn + idx];
        T[idx] = X0[row0*INNERn + idx];
    }
    if (t < 16) Sv[t] = S[row0 + t];
    __syncthreads();

    float c1[3];
    #pragma unroll
    for (int p = 0; p < 3; ++p) {
        int idx = t + 256*p;
        if (idx < 16*INNERn) {
            int r = idx / INNERn, c = idx - r*INNERn;
            float acc = bi[INNERn + c];             // b_inner[1][0][c]
            #pragma unroll 4
            for (int k = 0; k < INNERn; ++k) acc = fmaf(A[r*INNERn + k], W1[k*INNERn + c], acc);
            c1[p] = acc;
        }
    }
    __syncthreads();
    #pragma unroll
    for (int p = 0; p < 3; ++p) {
        int idx = t + 256*p;
        if (idx < 16*INNERn) {
            int r = idx / INNERn;
            X1[row0*INNERn + idx] = c1[p];
            A[idx] = A[idx] + Sv[r] * (c1[p] - T[idx]);   // pre2
        }
    }
    __syncthreads();
    #pragma unroll
    for (int p = 0; p < 3; ++p) {
        int idx = t + 256*p;
        if (idx < 16*INNERn) {
            int r = idx / INNERn, c = idx - r*INNERn;
            float acc = bi[2*INNERn + c];           // b_inner[2][0][c]
            #pragma unroll 4
            for (int k = 0; k < INNERn; ++k) acc = fmaf(A[r*INNERn + k], W2[k*INNERn + c], acc);
            X2[row0*INNERn + idx] = acc;
        }
    }
}

// Kernel 3: block = (d, b, 64-row chunk); wave handles 16 rows, lane owns 8
// contiguous cols. Halved W-load instruction count per FMA vs 8-rows/wave.
__global__ __launch_bounds__(256, 2) void k3_softmax(
    const float* __restrict__ X, const float* __restrict__ Wo,
    const float* __restrict__ bo_g, float* __restrict__ out)
{
    __shared__ float lx[64*INNERn];
    __shared__ float lacc4[4*OUTn];
    const int t = threadIdx.x;
    const int lane = t & 63;
    const int w = t >> 6;
    const int bx = blockIdx.x;
    const int d = bx >> 8;            // grid = 3 * 128 * 2 = 768
    const int rem = bx & 255;
    const int b = rem >> 1;
    const int chunk = rem & 1;

    const float* __restrict__ Xb = X + (((size_t)d*Bn + b)*Nn + chunk*64)*INNERn;
    for (int idx = t; idx < 64*INNERn; idx += 256) lx[idx] = Xb[idx];
    __syncthreads();

    const float* __restrict__ W = Wo + (size_t)d*INNERn*OUTn + lane*8;
    float acc[16][8];
    #pragma unroll
    for (int r = 0; r < 16; ++r)
        #pragma unroll
        for (int u = 0; u < 8; ++u) acc[r][u] = 0.f;

    for (int k = 0; k < INNERn; ++k) {
        const float4* __restrict__ wp = (const float4*)(W + k*OUTn);
        float4 w0 = wp[0];
        float4 w1 = wp[1];
        float wv[8] = {w0.x, w0.y, w0.z, w0.w, w1.x, w1.y, w1.z, w1.w};
        #pragma unroll
        for (int r = 0; r < 16; ++r) {
            float a = lx[(w*16 + r)*INNERn + k];                       // LDS broadcast
            #pragma unroll
            for (int u = 0; u < 8; ++u) acc[r][u] = fmaf(a, wv[u], acc[r][u]);
        }
    }

    const float4* __restrict__ bp = (const float4*)(bo_g + d*OUTn + lane*8);
    float4 b0 = bp[0];
    float4 b1 = bp[1];
    float bv[8] = {b0.x, b0.y, b0.z, b0.w, b1.x, b1.y, b1.z, b1.w};
    float colacc[8];
    #pragma unroll
    for (int u = 0; u < 8; ++u) colacc[u] = 0.f;

    #pragma unroll
    for (int r = 0; r < 16; ++r) {
        float lg[8];
        float m = -3.4e38f;
        #pragma unroll
        for (int u = 0; u < 8; ++u) { lg[u] = acc[r][u] + bv[u]; m = fmaxf(m, lg[u]); }
        #pragma unroll
        for (int off = 32; off > 0; off >>= 1) m = fmaxf(m, __shfl_xor(m, off));
        float s = 0.f, e[8];
        #pragma unroll
        for (int u = 0; u < 8; ++u) { e[u] = __expf(lg[u] - m); s += e[u]; }
        #pragma unroll
        for (int off = 32; off > 0; off >>= 1) s += __shfl_xor(s, off);
        float inv = 1.f / s;
        #pragma unroll
        for (int u = 0; u < 8; ++u) colacc[u] = fmaf(e[u], inv, colacc[u]);
    }

    // per-wave private segment: plain stores, contiguous per lane
    #pragma unroll
    for (int u = 0; u < 8; ++u) lacc4[w*OUTn + lane*8 + u] = colacc[u];
    __syncthreads();
    for (int idx = t; idx < OUTn; idx += 256) {
        float s = lacc4[idx] + lacc4[OUTn + idx] + lacc4[2*OUTn + idx] + lacc4[3*OUTn + idx];
        atomicAdd(&out[(size_t)b*OUTn + idx], s);
    }
}

extern "C" void kernel_launch(void* const* d_in, const int* in_sizes, int n_in,
                              void* d_out, int out_size, void* d_ws, size_t ws_size,
                              hipStream_t stream) {
    const float* g        = (const float*)d_in[0];  // (B,N,N,F)
    const float* W_inner  = (const float*)d_in[1];  // (3,40,40)
    const float* b_inner  = (const float*)d_in[2];  // (3,1,40)
    const float* W_output = (const float*)d_in[3];  // (3,40,512)
    const float* b_output = (const float*)d_in[4];  // (3,1,512)
    float* out = (float*)d_out;                     // (B,512) fp32
    float* ws  = (float*)d_ws;

    // ws layout (floats): X[3][B*N][40] | pre1[B*N][40] | S[B*N]
    const size_t nBN = (size_t)Bn * Nn;
    float* X    = ws;
    float* X0   = X;
    float* X1   = X + nBN * INNERn;
    float* X2   = X + 2 * nBN * INNERn;
    float* pre1 = X + 3 * nBN * INNERn;
    float* S    = pre1 + nBN * INNERn;

    k0_zero<<<256, 256, 0, stream>>>(S, out);
    k1_reduce<<<Bn*Nn, 256, 0, stream>>>(g, X0, pre1, S);
    k2_chain<<<(Bn*Nn)/16, 256, 0, stream>>>(pre1, X0, S, W_inner, b_inner, X1, X2);
    k3_softmax<<<3*Bn*2, 256, 0, stream>>>(X, W_output, b_output, out);
}